// Round 1
// 1504.576 us; speedup vs baseline: 3.1997x; 3.1997x over previous
//
#include <hip/hip_runtime.h>
#include <math.h>

#define TOKENS 112896
#define C      384
#define NQKV   1152
#define NFC    1536
#define HEADS  6
#define HD     64
#define WIN    14
#define L      196
#define NWS    24
#define SCALEF 0.125f

typedef unsigned int  u32;
typedef unsigned short u16;
typedef short short8 __attribute__((ext_vector_type(8)));
typedef float floatx4 __attribute__((ext_vector_type(4)));

__device__ __forceinline__ u16 f2bf(float f) {
  u32 u = __float_as_uint(f);
  u += 0x7FFFu + ((u >> 16) & 1u);   // RNE (finite values only here)
  return (u16)(u >> 16);
}

__device__ __forceinline__ float bf2f(u16 v) {
  return __uint_as_float((u32)v << 16);
}

// async 16B global->LDS copy; lds base must be wave-uniform, HW adds lane*16
__device__ __forceinline__ void async16(u16* lds, const u16* g) {
  __builtin_amdgcn_global_load_lds((const __attribute__((address_space(1))) void*)g,
                                   (__attribute__((address_space(3))) void*)lds,
                                   16, 0, 0);
}

__device__ __forceinline__ int win_to_tok(int r) {
  int n = r / L, l = r % L;
  int wh = n / NWS, ww = n % NWS;
  int ih = l / WIN, iw = l % WIN;
  return (wh * WIN + ih) * 336 + ww * WIN + iw;
}

// ---------------------------------------------------------------- weight T+cvt
__global__ __launch_bounds__(256) void conv_t_kernel(const float* __restrict__ in,
    u16* __restrict__ out, int K, int N)
{
  int idx = blockIdx.x * 256 + threadIdx.x;
  if (idx >= K * N) return;
  int n = idx / K, k = idx % K;
  out[idx] = f2bf(in[(size_t)k * N + n]);
}

// ---------------------------------------------------------------- LayerNorm
template<bool PERMUTE>
__global__ __launch_bounds__(128) void ln_kernel(const float* __restrict__ x,
    const float* __restrict__ w, const float* __restrict__ b,
    u16* __restrict__ out)
{
  const int t = blockIdx.x;
  const int tid = threadIdx.x;
  const float* xr = x + (size_t)t * C;
  float v0 = xr[tid], v1 = xr[tid + 128], v2 = xr[tid + 256];
  float s  = v0 + v1 + v2;
  float ss = v0 * v0 + v1 * v1 + v2 * v2;
#pragma unroll
  for (int off = 32; off > 0; off >>= 1) {
    s  += __shfl_down(s, off);
    ss += __shfl_down(ss, off);
  }
  __shared__ float red[4];
  if ((tid & 63) == 0) { red[(tid >> 6) * 2 + 0] = s; red[(tid >> 6) * 2 + 1] = ss; }
  __syncthreads();
  float S  = red[0] + red[2];
  float SS = red[1] + red[3];
  float mean = S * (1.0f / C);
  float var  = SS * (1.0f / C) - mean * mean;
  float rstd = rsqrtf(var + 1e-5f);
  size_t orow;
  if (PERMUTE) {
    int h_ = t / 336, w_ = t % 336;
    int wh = h_ / WIN, ih = h_ % WIN;
    int ww = w_ / WIN, iw = w_ % WIN;
    orow = (size_t)((wh * NWS + ww) * L + ih * WIN + iw);
  } else {
    orow = (size_t)t;
  }
  u16* op = out + orow * C;
  op[tid]       = f2bf((v0 - mean) * rstd * w[tid]       + b[tid]);
  op[tid + 128] = f2bf((v1 - mean) * rstd * w[tid + 128] + b[tid + 128]);
  op[tid + 256] = f2bf((v2 - mean) * rstd * w[tid + 256] + b[tid + 256]);
}

// ---------------------------------------------------------------- bf16 MFMA GEMM
template<int MODE>
__global__ __launch_bounds__(256) void gemm_bf16(
    const u16* __restrict__ A, const u16* __restrict__ Bt,
    const float* __restrict__ bias, const float* __restrict__ res,
    void* __restrict__ outv, int N, int K)
{
  __shared__ u16 As[128 * 32];
  __shared__ u16 Bs[128 * 32];
  const int tid = threadIdx.x;
  const int w = tid >> 6, l = tid & 63;
  const int bm = blockIdx.y * 128, bn = blockIdx.x * 128;
  const int wm = (w >> 1) * 64, wn = (w & 1) * 64;
  const int lm = l & 15, quad = l >> 4;

  floatx4 acc[4][4] = {};

  const int srow = tid >> 2, sseg = tid & 3;
  const u16* Ag0 = A  + (size_t)(bm + srow)      * K + sseg * 8;
  const u16* Ag1 = A  + (size_t)(bm + srow + 64) * K + sseg * 8;
  const u16* Bg0 = Bt + (size_t)(bn + srow)      * K + sseg * 8;
  const u16* Bg1 = Bt + (size_t)(bn + srow + 64) * K + sseg * 8;
  u16* Asw0 = As + w * 512;
  u16* Asw1 = As + 2048 + w * 512;
  u16* Bsw0 = Bs + w * 512;
  u16* Bsw1 = Bs + 2048 + w * 512;

  for (int kt = 0; kt < K; kt += 32) {
    async16(Asw0, Ag0 + kt);
    async16(Asw1, Ag1 + kt);
    async16(Bsw0, Bg0 + kt);
    async16(Bsw1, Bg1 + kt);
    __syncthreads();
    short8 af[4], bf[4];
#pragma unroll
    for (int i = 0; i < 4; i++)
      af[i] = *(const short8*)(As + (wm + i * 16 + lm) * 32 + quad * 8);
#pragma unroll
    for (int j = 0; j < 4; j++)
      bf[j] = *(const short8*)(Bs + (wn + j * 16 + lm) * 32 + quad * 8);
#pragma unroll
    for (int i = 0; i < 4; i++)
#pragma unroll
      for (int j = 0; j < 4; j++)
        acc[i][j] = __builtin_amdgcn_mfma_f32_16x16x32_bf16(af[i], bf[j], acc[i][j], 0, 0, 0);
    __syncthreads();
  }

  const int colbase = bn + wn + lm;
  float bb[4];
#pragma unroll
  for (int j = 0; j < 4; j++) bb[j] = bias[colbase + j * 16];

#pragma unroll
  for (int i = 0; i < 4; i++) {
#pragma unroll
    for (int reg = 0; reg < 4; reg++) {
      int row = bm + wm + i * 16 + quad * 4 + reg;
      size_t ro;
      if (MODE == 1) ro = (size_t)win_to_tok(row) * N;
      else           ro = (size_t)row * N;
#pragma unroll
      for (int j = 0; j < 4; j++) {
        float v = acc[i][j][reg] + bb[j];
        int col = colbase + j * 16;
        if (MODE == 0) {
          ((u16*)outv)[ro + col] = f2bf(v);
        } else if (MODE == 1) {
          ((float*)outv)[ro + col] = v + res[ro + col];
        } else if (MODE == 2) {
          ((u16*)outv)[ro + col] = f2bf(0.5f * v * (1.0f + erff(v * 0.70710678118654752f)));
        } else {
          ((float*)outv)[ro + col] = v + res[ro + col];
        }
      }
    }
  }
}

// ---------------------------------------------------------------- MFMA Attention
// One block per (window, head); 4 waves, 256 threads; mfma_f32_16x16x32_bf16.
// Rows padded 196->208 = 13 row-tiles, wave w owns rt = w, w+4, w+8, (w+12).
// Q A-frags live in registers for the whole kernel. Rel-pos bias is computed
// as RH' = Q @ relh^T, RW' = Q @ relw^T ([196,27]) via MFMA into LDS (bf16);
// softmax bias = RH'[q, qh-kh+13] + RW'[q, qw-kw+13] (2 broadcast LDS reads).
// K staged [32][64] with 8-elem-granule XOR swizzle (conflict-free B-frag
// ds_read_b128); V staged transposed [64][40] so PV B-frags are b128 reads.
// P (post-exp) round-trips through a per-wave swizzled f32 LDS tile to
// convert MFMA C-layout (row=quad*4+reg, col=lane) into A-layout
// (row=lane, k=quad*8+j). In-wave DS ordering -> no barrier for P.
// Max-free softmax (logits O(1), validated by baseline); pad cols masked to
// p=0; staging rows clamped to 195 so no NaN can reach an MFMA.
__global__ __launch_bounds__(256, 2) void attn_kernel(
    const u16* __restrict__ qkv,
    const float* __restrict__ relh, const float* __restrict__ relw,
    u16* __restrict__ out)
{
  __shared__ float Plds[4][512];      // per-wave P tile [16][32] f32, 4-float-granule XOR swz
  __shared__ u16 rhlds[208 * 28];     // RH'[q][t] bf16
  __shared__ u16 rwlds[208 * 28];     // RW'[q][t] bf16
  __shared__ u16 Klds[32 * 64];       // K tile [kv][c] bf16, granule^(kv&7) swz
  __shared__ u16 Vtl[64 * 40];        // V^T tile [d][kv] bf16 (stride 40 for banks)

  const int n = blockIdx.x / HEADS;
  const int h = blockIdx.x % HEADS;
  const int tid = threadIdx.x;
  const int w = tid >> 6;
  const int l = tid & 63;
  const int lm = l & 15;
  const int quad = l >> 4;
  const size_t base = (size_t)n * L;

  // ---- Q A-fragments: registers for whole kernel (rows clamped; row>=196 discarded)
  short8 qf[4][2];
#pragma unroll
  for (int i = 0; i < 4; i++) {
    int rt = w + 4 * i;
    if (rt <= 12) {
      int row = rt * 16 + lm; if (row > 195) row = 195;
      const u16* qp = qkv + (base + row) * NQKV + h * HD + quad * 8;
#pragma unroll
      for (int kf = 0; kf < 2; kf++)
        qf[i][kf] = *(const short8*)(qp + kf * 32);
    }
  }

  // ---- RH'/RW' = Q @ rel_table^T -> LDS bf16 (per-wave rows; no barrier needed)
  {
    short8 tf[2][2][2];  // [tab][ct][kf]
#pragma unroll
    for (int tab = 0; tab < 2; tab++) {
      const float* tp = tab ? relw : relh;
#pragma unroll
      for (int ct = 0; ct < 2; ct++) {
        int t = ct * 16 + lm;
#pragma unroll
        for (int kf = 0; kf < 2; kf++) {
          short8 v = {0, 0, 0, 0, 0, 0, 0, 0};
          if (t < 27) {
            const float* p = tp + t * HD + kf * 32 + quad * 8;
            float4 a = *(const float4*)p;
            float4 b = *(const float4*)(p + 4);
            v[0] = (short)f2bf(a.x); v[1] = (short)f2bf(a.y);
            v[2] = (short)f2bf(a.z); v[3] = (short)f2bf(a.w);
            v[4] = (short)f2bf(b.x); v[5] = (short)f2bf(b.y);
            v[6] = (short)f2bf(b.z); v[7] = (short)f2bf(b.w);
          }
          tf[tab][ct][kf] = v;
        }
      }
    }
#pragma unroll
    for (int i = 0; i < 4; i++) {
      int rt = w + 4 * i;
      if (rt > 12) continue;
#pragma unroll
      for (int tab = 0; tab < 2; tab++) {
        u16* dst = tab ? rwlds : rhlds;
#pragma unroll
        for (int ct = 0; ct < 2; ct++) {
          floatx4 acc = {};
          acc = __builtin_amdgcn_mfma_f32_16x16x32_bf16(qf[i][0], tf[tab][ct][0], acc, 0, 0, 0);
          acc = __builtin_amdgcn_mfma_f32_16x16x32_bf16(qf[i][1], tf[tab][ct][1], acc, 0, 0, 0);
          int t = ct * 16 + lm;
          if (t < 28) {
#pragma unroll
            for (int reg = 0; reg < 4; reg++) {
              int q = rt * 16 + quad * 4 + reg;
              dst[q * 28 + t] = f2bf(acc[reg]);
            }
          }
        }
      }
    }
  }

  floatx4 oacc[4][4] = {};   // [i][dt]
  float lsum[4][4] = {};     // [i][reg]

#pragma unroll 1
  for (int ks = 0; ks < 7; ks++) {
    __syncthreads();   // all waves done reading Klds/Vtl from previous step
    // stage K [32][64], granule g -> g ^ (r&7)
    {
      int r = tid >> 3, g = tid & 7;
      int row = ks * 32 + r; if (row > 195) row = 195;
      uint4 kd = *(const uint4*)(qkv + (base + row) * NQKV + C + h * HD + g * 8);
      *(uint4*)&Klds[r * 64 + ((g ^ (r & 7)) * 8)] = kd;
    }
    // stage V^T [64][40]
    {
      int r = tid & 31, seg = tid >> 5;
      int row = ks * 32 + r; if (row > 195) row = 195;
      uint4 vd = *(const uint4*)(qkv + (base + row) * NQKV + 2 * C + h * HD + seg * 8);
      union { uint4 u; u16 s[8]; } vv; vv.u = vd;
#pragma unroll
      for (int j = 0; j < 8; j++) Vtl[(seg * 8 + j) * 40 + r] = vv.s[j];
    }
    __syncthreads();

    // K B-frags: B[c][kv], lane col=kv=ct*16+lm, c=kf*32+quad*8+j
    short8 kfr[2][2];
#pragma unroll
    for (int ct = 0; ct < 2; ct++) {
      int krow = ct * 16 + lm;
#pragma unroll
      for (int kf = 0; kf < 2; kf++)
        kfr[ct][kf] = *(const short8*)&Klds[krow * 64 + (((kf * 4 + quad) ^ (krow & 7)) * 8)];
    }
    // V B-frags: B[kv][d], lane col=d=dt*16+lm, kv=quad*8+j
    short8 vfr[4];
#pragma unroll
    for (int dt = 0; dt < 4; dt++)
      vfr[dt] = *(const short8*)&Vtl[(dt * 16 + lm) * 40 + quad * 8];

#pragma unroll
    for (int i = 0; i < 4; i++) {
      int rt = w + 4 * i;
      if (rt > 12) continue;
      // S tile: [16 q][32 kv]
      floatx4 sc[2] = {};
#pragma unroll
      for (int ct = 0; ct < 2; ct++) {
        sc[ct] = __builtin_amdgcn_mfma_f32_16x16x32_bf16(qf[i][0], kfr[ct][0], sc[ct], 0, 0, 0);
        sc[ct] = __builtin_amdgcn_mfma_f32_16x16x32_bf16(qf[i][1], kfr[ct][1], sc[ct], 0, 0, 0);
      }
      float* Pw = Plds[w];
#pragma unroll
      for (int ct = 0; ct < 2; ct++) {
        int k = ks * 32 + ct * 16 + lm;
        int kh = (k * 293) >> 12;       // k/14, exact for k < ~580
        int kw2 = k - kh * 14;
        bool kval = (k < 196);
#pragma unroll
        for (int reg = 0; reg < 4; reg++) {
          int q = rt * 16 + quad * 4 + reg;
          int qh = (q * 293) >> 12;
          int qw = q - qh * 14;
          int th = qh - kh + 13; th = th < 0 ? 0 : th;   // pad cols can go to -2; masked anyway
          int tw = qw - kw2 + 13;
          float bh = bf2f(rhlds[q * 28 + th]);
          float bw = bf2f(rwlds[q * 28 + tw]);
          float s = sc[ct][reg] * SCALEF + bh + bw;
          float p = kval ? __expf(s) : 0.0f;
          lsum[i][reg] += p;
          int prow = quad * 4 + reg;
          int col = ct * 16 + lm;
          Pw[prow * 32 + (((col >> 2) ^ (prow & 7)) * 4) + (col & 3)] = p;
        }
      }
      // P A-frag: row=lm, k=quad*8+j (in-wave DS ordering: writes above land first)
      floatx4 pa = *(const floatx4*)&Pw[lm * 32 + (((2 * quad) ^ (lm & 7)) * 4)];
      floatx4 pb = *(const floatx4*)&Pw[lm * 32 + (((2 * quad + 1) ^ (lm & 7)) * 4)];
      short8 pfr;
#pragma unroll
      for (int j = 0; j < 4; j++) {
        pfr[j]     = (short)f2bf(pa[j]);
        pfr[4 + j] = (short)f2bf(pb[j]);
      }
#pragma unroll
      for (int dt = 0; dt < 4; dt++)
        oacc[i][dt] = __builtin_amdgcn_mfma_f32_16x16x32_bf16(pfr, vfr[dt], oacc[i][dt], 0, 0, 0);
    }
  }

  // ---- epilogue: row-sum across the 16 lanes of each quad group, normalize, store
#pragma unroll
  for (int i = 0; i < 4; i++) {
    int rt = w + 4 * i;
    if (rt > 12) continue;
#pragma unroll
    for (int reg = 0; reg < 4; reg++) {
      float v = lsum[i][reg];
      v += __shfl_xor(v, 1);
      v += __shfl_xor(v, 2);
      v += __shfl_xor(v, 4);
      v += __shfl_xor(v, 8);
      float inv = 1.0f / v;
      int row = rt * 16 + quad * 4 + reg;
      if (row < 196) {
        u16* op = out + (base + row) * C + h * HD + lm;
#pragma unroll
        for (int dt = 0; dt < 4; dt++) op[dt * 16] = f2bf(oacc[i][dt][reg] * inv);
      }
    }
  }
}

// ---------------------------------------------------------------- launch
extern "C" void kernel_launch(void* const* d_in, const int* in_sizes, int n_in,
                              void* d_out, int out_size, void* d_ws, size_t ws_size,
                              hipStream_t stream)
{
  const float* x      = (const float*)d_in[0];
  const float* qkv_w  = (const float*)d_in[1];
  const float* qkv_b  = (const float*)d_in[2];
  const float* proj_w = (const float*)d_in[3];
  const float* proj_b = (const float*)d_in[4];
  const float* rel_h  = (const float*)d_in[5];
  const float* rel_w  = (const float*)d_in[6];
  const float* n1w    = (const float*)d_in[7];
  const float* n1b    = (const float*)d_in[8];
  const float* n2w    = (const float*)d_in[9];
  const float* n2b    = (const float*)d_in[10];
  const float* fc1_w  = (const float*)d_in[11];
  const float* fc1_b  = (const float*)d_in[12];
  const float* fc2_w  = (const float*)d_in[13];
  const float* fc2_b  = (const float*)d_in[14];

  // workspace: [W0: M*384 bf16][W1: M*1536 bf16][W2: M*384 f32][WT: weights bf16]
  u16*  W0 = (u16*)d_ws;
  u16*  W1 = (u16*)((char*)d_ws + 86704128);
  float* W2 = (float*)((char*)d_ws + 86704128 + 346816512);
  u16*  WT = (u16*)((char*)d_ws + 86704128 + 346816512 + 173408256);
  u16* qkv_wT  = WT;                   // [1152,384]
  u16* proj_wT = qkv_wT + 442368;      // [384,384]
  u16* fc1_wT  = proj_wT + 147456;     // [1536,384]
  u16* fc2_wT  = fc1_wT + 589824;      // [384,1536]

  conv_t_kernel<<<(442368 + 255) / 256, 256, 0, stream>>>(qkv_w, qkv_wT, C, NQKV);
  conv_t_kernel<<<(147456 + 255) / 256, 256, 0, stream>>>(proj_w, proj_wT, C, C);
  conv_t_kernel<<<(589824 + 255) / 256, 256, 0, stream>>>(fc1_w, fc1_wT, C, NFC);
  conv_t_kernel<<<(589824 + 255) / 256, 256, 0, stream>>>(fc2_w, fc2_wT, NFC, C);

  // 1. LN1 + window partition -> bf16
  ln_kernel<true><<<TOKENS, 128, 0, stream>>>(x, n1w, n1b, W0);
  // 2. qkv = xw @ qkv_w + b  -> bf16 [M,1152]
  gemm_bf16<0><<<dim3(NQKV / 128, TOKENS / 128), 256, 0, stream>>>(
      W0, qkv_wT, qkv_b, nullptr, W1, NQKV, C);
  // 3. MFMA attention -> attn_out bf16 (windowed rows) in W0
  attn_kernel<<<576 * HEADS, 256, 0, stream>>>(W1, rel_h, rel_w, W0);
  // 4. x2 = x + attn_out @ proj_w + b (unpartition remap) -> f32
  gemm_bf16<1><<<dim3(C / 128, TOKENS / 128), 256, 0, stream>>>(
      W0, proj_wT, proj_b, x, W2, C, C);
  // 5. LN2 -> bf16
  ln_kernel<false><<<TOKENS, 128, 0, stream>>>(W2, n2w, n2b, W0);
  // 6. h1 = gelu(xn2 @ fc1_w + b) -> bf16 [M,1536]
  gemm_bf16<2><<<dim3(NFC / 128, TOKENS / 128), 256, 0, stream>>>(
      W0, fc1_wT, fc1_b, nullptr, W1, NFC, C);
  // 7. out = x2 + h1 @ fc2_w + b -> f32
  gemm_bf16<3><<<dim3(C / 128, TOKENS / 128), 256, 0, stream>>>(
      W1, fc2_wT, fc2_b, W2, (float*)d_out, C, NFC);
}

// Round 2
// 1481.812 us; speedup vs baseline: 3.2489x; 1.0154x over previous
//
#include <hip/hip_runtime.h>
#include <math.h>

#define TOKENS 112896
#define C      384
#define NQKV   1152
#define NFC    1536
#define HEADS  6
#define HD     64
#define WIN    14
#define L      196
#define NWS    24
#define SCALEF 0.125f

typedef unsigned int  u32;
typedef unsigned short u16;
typedef short short8 __attribute__((ext_vector_type(8)));
typedef float floatx4 __attribute__((ext_vector_type(4)));

__device__ __forceinline__ u16 f2bf(float f) {
  u32 u = __float_as_uint(f);
  u += 0x7FFFu + ((u >> 16) & 1u);   // RNE (finite values only here)
  return (u16)(u >> 16);
}

__device__ __forceinline__ float bf2f(u16 v) {
  return __uint_as_float((u32)v << 16);
}

// async 16B global->LDS copy; lds base must be wave-uniform, HW adds lane*16
__device__ __forceinline__ void async16(u16* lds, const u16* g) {
  __builtin_amdgcn_global_load_lds((const __attribute__((address_space(1))) void*)g,
                                   (__attribute__((address_space(3))) void*)lds,
                                   16, 0, 0);
}

__device__ __forceinline__ int win_to_tok(int r) {
  int n = r / L, l = r % L;
  int wh = n / NWS, ww = n % NWS;
  int ih = l / WIN, iw = l % WIN;
  return (wh * WIN + ih) * 336 + ww * WIN + iw;
}

// ---------------------------------------------------------------- weight T+cvt
// out[n*K+k] = bf16(in[k*N+n]); 32x32 LDS tile transpose, coalesced both sides.
// grid (N/32, K/32), 256 threads (32x8, 4 rows per thread).
__global__ __launch_bounds__(256) void conv_t_kernel(const float* __restrict__ in,
    u16* __restrict__ out, int K, int N)
{
  __shared__ u16 tile[32][33];
  const int kb = blockIdx.y * 32, nb = blockIdx.x * 32;
  const int tx = threadIdx.x & 31, ty = threadIdx.x >> 5;
#pragma unroll
  for (int i = 0; i < 4; i++) {
    int k = kb + ty + i * 8;
    tile[ty + i * 8][tx] = f2bf(in[(size_t)k * N + nb + tx]);
  }
  __syncthreads();
#pragma unroll
  for (int i = 0; i < 4; i++) {
    int n = nb + ty + i * 8;
    out[(size_t)n * K + kb + tx] = tile[tx][ty + i * 8];
  }
}

// ---------------------------------------------------------------- LayerNorm
template<bool PERMUTE>
__global__ __launch_bounds__(128) void ln_kernel(const float* __restrict__ x,
    const float* __restrict__ w, const float* __restrict__ b,
    u16* __restrict__ out)
{
  const int t = blockIdx.x;
  const int tid = threadIdx.x;
  const float* xr = x + (size_t)t * C;
  float v0 = xr[tid], v1 = xr[tid + 128], v2 = xr[tid + 256];
  float s  = v0 + v1 + v2;
  float ss = v0 * v0 + v1 * v1 + v2 * v2;
#pragma unroll
  for (int off = 32; off > 0; off >>= 1) {
    s  += __shfl_down(s, off);
    ss += __shfl_down(ss, off);
  }
  __shared__ float red[4];
  if ((tid & 63) == 0) { red[(tid >> 6) * 2 + 0] = s; red[(tid >> 6) * 2 + 1] = ss; }
  __syncthreads();
  float S  = red[0] + red[2];
  float SS = red[1] + red[3];
  float mean = S * (1.0f / C);
  float var  = SS * (1.0f / C) - mean * mean;
  float rstd = rsqrtf(var + 1e-5f);
  size_t orow;
  if (PERMUTE) {
    int h_ = t / 336, w_ = t % 336;
    int wh = h_ / WIN, ih = h_ % WIN;
    int ww = w_ / WIN, iw = w_ % WIN;
    orow = (size_t)((wh * NWS + ww) * L + ih * WIN + iw);
  } else {
    orow = (size_t)t;
  }
  u16* op = out + orow * C;
  op[tid]       = f2bf((v0 - mean) * rstd * w[tid]       + b[tid]);
  op[tid + 128] = f2bf((v1 - mean) * rstd * w[tid + 128] + b[tid + 128]);
  op[tid + 256] = f2bf((v2 - mean) * rstd * w[tid + 256] + b[tid + 256]);
}

// ---------------------------------------------------------------- bf16 MFMA GEMM
// A[M,K] bf16 row-major, Bt[N,K] bf16 row-major. 128x128 tile, BK=64,
// double-buffered LDS with depth-1 prefetch (stage t+1 issued before compute
// of t; single __syncthreads per k-step drains vmcnt after compute -> loads
// fly under the 32 MFMAs). LDS rows are 128B with 8x16B granules; bank
// conflicts killed by XOR swizzle done on the GLOBAL source address
// (global_load_lds writes linearly; LDS[r][g] holds global granule g^(r&7),
// reads apply the same XOR). Bijective XCD swizzle (m204) for A-panel L2 reuse.
template<int MODE>
__global__ __launch_bounds__(256, 2) void gemm_bf16(
    const u16* __restrict__ A, const u16* __restrict__ Bt,
    const float* __restrict__ bias, const float* __restrict__ res,
    void* __restrict__ outv, int N, int K)
{
  __shared__ u16 As[2][128 * 64];
  __shared__ u16 Bs[2][128 * 64];
  const int tid = threadIdx.x;
  const int w = tid >> 6, l = tid & 63;

  // bijective XCD-chunked remap of linear block id
  const int nwg = gridDim.x * gridDim.y;
  int lin = blockIdx.y * gridDim.x + blockIdx.x;
  {
    int q8 = nwg >> 3, r8 = nwg & 7;
    int xcd = lin & 7, sub = lin >> 3;
    lin = (xcd < r8 ? xcd * (q8 + 1) : r8 * (q8 + 1) + (xcd - r8) * q8) + sub;
  }
  const int bx = lin % gridDim.x, by = lin / gridDim.x;
  const int bm = by * 128, bn = bx * 128;

  const int wm = (w >> 1) * 64, wn = (w & 1) * 64;
  const int lm = l & 15, quad = l >> 4;

  floatx4 acc[4][4] = {};

  // staging geometry: per wave, part p covers rows p*32 + w*8 + (l>>3),
  // lane granule (l&7); source granule pre-swizzled by row&7 == l>>3.
  const int srow8 = l >> 3;
  const int sgran = (l & 7) ^ srow8;
  const u16* Ag[4];
  const u16* Bg[4];
#pragma unroll
  for (int p = 0; p < 4; p++) {
    Ag[p] = A  + (size_t)(bm + p * 32 + w * 8 + srow8) * K + sgran * 8;
    Bg[p] = Bt + (size_t)(bn + p * 32 + w * 8 + srow8) * K + sgran * 8;
  }

  auto stage = [&](int buf, int kt) {
#pragma unroll
    for (int p = 0; p < 4; p++) {
      async16(&As[buf][(p * 32 + w * 8) * 64], Ag[p] + kt);
      async16(&Bs[buf][(p * 32 + w * 8) * 64], Bg[p] + kt);
    }
  };

  const int nk = K >> 6;
  stage(0, 0);
  __syncthreads();   // drains vmcnt(0): tile 0 resident

  for (int t = 0; t < nk; t++) {
    const int buf = t & 1;
    if (t + 1 < nk) stage(buf ^ 1, (t + 1) << 6);

    short8 af[4][2], bf[4][2];
#pragma unroll
    for (int i = 0; i < 4; i++) {
      int r = wm + i * 16 + lm, sw = r & 7;
      af[i][0] = *(const short8*)(&As[buf][r * 64 + ((quad ^ sw) * 8)]);
      af[i][1] = *(const short8*)(&As[buf][r * 64 + (((4 + quad) ^ sw) * 8)]);
    }
#pragma unroll
    for (int j = 0; j < 4; j++) {
      int r = wn + j * 16 + lm, sw = r & 7;
      bf[j][0] = *(const short8*)(&Bs[buf][r * 64 + ((quad ^ sw) * 8)]);
      bf[j][1] = *(const short8*)(&Bs[buf][r * 64 + (((4 + quad) ^ sw) * 8)]);
    }
#pragma unroll
    for (int i = 0; i < 4; i++)
#pragma unroll
      for (int j = 0; j < 4; j++) {
        acc[i][j] = __builtin_amdgcn_mfma_f32_16x16x32_bf16(af[i][0], bf[j][0], acc[i][j], 0, 0, 0);
        acc[i][j] = __builtin_amdgcn_mfma_f32_16x16x32_bf16(af[i][1], bf[j][1], acc[i][j], 0, 0, 0);
      }
    __syncthreads();   // prefetch landed (auto vmcnt drain) + all reads of buf done
  }

  // epilogue; C/D layout: col = lane&15, row = quad*4 + reg
  const int colbase = bn + wn + lm;
  float bb[4];
#pragma unroll
  for (int j = 0; j < 4; j++) bb[j] = bias[colbase + j * 16];

#pragma unroll
  for (int i = 0; i < 4; i++) {
#pragma unroll
    for (int reg = 0; reg < 4; reg++) {
      int row = bm + wm + i * 16 + quad * 4 + reg;
      size_t ro;
      if (MODE == 1) ro = (size_t)win_to_tok(row) * N;
      else           ro = (size_t)row * N;
#pragma unroll
      for (int j = 0; j < 4; j++) {
        float v = acc[i][j][reg] + bb[j];
        int col = colbase + j * 16;
        if (MODE == 0) {
          ((u16*)outv)[ro + col] = f2bf(v);
        } else if (MODE == 1) {
          ((float*)outv)[ro + col] = v + res[ro + col];
        } else if (MODE == 2) {
          ((u16*)outv)[ro + col] = f2bf(0.5f * v * (1.0f + erff(v * 0.70710678118654752f)));
        } else {
          ((float*)outv)[ro + col] = v + res[ro + col];
        }
      }
    }
  }
}

// ---------------------------------------------------------------- MFMA Attention
// One block per (window, head); 4 waves, 256 threads; mfma_f32_16x16x32_bf16.
// (unchanged from round 1 — no longer the bottleneck)
__global__ __launch_bounds__(256, 2) void attn_kernel(
    const u16* __restrict__ qkv,
    const float* __restrict__ relh, const float* __restrict__ relw,
    u16* __restrict__ out)
{
  __shared__ float Plds[4][512];      // per-wave P tile [16][32] f32, 4-float-granule XOR swz
  __shared__ u16 rhlds[208 * 28];     // RH'[q][t] bf16
  __shared__ u16 rwlds[208 * 28];     // RW'[q][t] bf16
  __shared__ u16 Klds[32 * 64];       // K tile [kv][c] bf16, granule^(kv&7) swz
  __shared__ u16 Vtl[64 * 40];        // V^T tile [d][kv] bf16 (stride 40 for banks)

  const int n = blockIdx.x / HEADS;
  const int h = blockIdx.x % HEADS;
  const int tid = threadIdx.x;
  const int w = tid >> 6;
  const int l = tid & 63;
  const int lm = l & 15;
  const int quad = l >> 4;
  const size_t base = (size_t)n * L;

  // ---- Q A-fragments: registers for whole kernel (rows clamped; row>=196 discarded)
  short8 qf[4][2];
#pragma unroll
  for (int i = 0; i < 4; i++) {
    int rt = w + 4 * i;
    if (rt <= 12) {
      int row = rt * 16 + lm; if (row > 195) row = 195;
      const u16* qp = qkv + (base + row) * NQKV + h * HD + quad * 8;
#pragma unroll
      for (int kf = 0; kf < 2; kf++)
        qf[i][kf] = *(const short8*)(qp + kf * 32);
    }
  }

  // ---- RH'/RW' = Q @ rel_table^T -> LDS bf16 (per-wave rows; no barrier needed)
  {
    short8 tf[2][2][2];  // [tab][ct][kf]
#pragma unroll
    for (int tab = 0; tab < 2; tab++) {
      const float* tp = tab ? relw : relh;
#pragma unroll
      for (int ct = 0; ct < 2; ct++) {
        int t = ct * 16 + lm;
#pragma unroll
        for (int kf = 0; kf < 2; kf++) {
          short8 v = {0, 0, 0, 0, 0, 0, 0, 0};
          if (t < 27) {
            const float* p = tp + t * HD + kf * 32 + quad * 8;
            float4 a = *(const float4*)p;
            float4 b = *(const float4*)(p + 4);
            v[0] = (short)f2bf(a.x); v[1] = (short)f2bf(a.y);
            v[2] = (short)f2bf(a.z); v[3] = (short)f2bf(a.w);
            v[4] = (short)f2bf(b.x); v[5] = (short)f2bf(b.y);
            v[6] = (short)f2bf(b.z); v[7] = (short)f2bf(b.w);
          }
          tf[tab][ct][kf] = v;
        }
      }
    }
#pragma unroll
    for (int i = 0; i < 4; i++) {
      int rt = w + 4 * i;
      if (rt > 12) continue;
#pragma unroll
      for (int tab = 0; tab < 2; tab++) {
        u16* dst = tab ? rwlds : rhlds;
#pragma unroll
        for (int ct = 0; ct < 2; ct++) {
          floatx4 acc = {};
          acc = __builtin_amdgcn_mfma_f32_16x16x32_bf16(qf[i][0], tf[tab][ct][0], acc, 0, 0, 0);
          acc = __builtin_amdgcn_mfma_f32_16x16x32_bf16(qf[i][1], tf[tab][ct][1], acc, 0, 0, 0);
          int t = ct * 16 + lm;
          if (t < 28) {
#pragma unroll
            for (int reg = 0; reg < 4; reg++) {
              int q = rt * 16 + quad * 4 + reg;
              dst[q * 28 + t] = f2bf(acc[reg]);
            }
          }
        }
      }
    }
  }

  floatx4 oacc[4][4] = {};   // [i][dt]
  float lsum[4][4] = {};     // [i][reg]

#pragma unroll 1
  for (int ks = 0; ks < 7; ks++) {
    __syncthreads();   // all waves done reading Klds/Vtl from previous step
    // stage K [32][64], granule g -> g ^ (r&7)
    {
      int r = tid >> 3, g = tid & 7;
      int row = ks * 32 + r; if (row > 195) row = 195;
      uint4 kd = *(const uint4*)(qkv + (base + row) * NQKV + C + h * HD + g * 8);
      *(uint4*)&Klds[r * 64 + ((g ^ (r & 7)) * 8)] = kd;
    }
    // stage V^T [64][40]
    {
      int r = tid & 31, seg = tid >> 5;
      int row = ks * 32 + r; if (row > 195) row = 195;
      uint4 vd = *(const uint4*)(qkv + (base + row) * NQKV + 2 * C + h * HD + seg * 8);
      union { uint4 u; u16 s[8]; } vv; vv.u = vd;
#pragma unroll
      for (int j = 0; j < 8; j++) Vtl[(seg * 8 + j) * 40 + r] = vv.s[j];
    }
    __syncthreads();

    // K B-frags: B[c][kv], lane col=kv=ct*16+lm, c=kf*32+quad*8+j
    short8 kfr[2][2];
#pragma unroll
    for (int ct = 0; ct < 2; ct++) {
      int krow = ct * 16 + lm;
#pragma unroll
      for (int kf = 0; kf < 2; kf++)
        kfr[ct][kf] = *(const short8*)&Klds[krow * 64 + (((kf * 4 + quad) ^ (krow & 7)) * 8)];
    }
    // V B-frags: B[kv][d], lane col=d=dt*16+lm, kv=quad*8+j
    short8 vfr[4];
#pragma unroll
    for (int dt = 0; dt < 4; dt++)
      vfr[dt] = *(const short8*)&Vtl[(dt * 16 + lm) * 40 + quad * 8];

#pragma unroll
    for (int i = 0; i < 4; i++) {
      int rt = w + 4 * i;
      if (rt > 12) continue;
      // S tile: [16 q][32 kv]
      floatx4 sc[2] = {};
#pragma unroll
      for (int ct = 0; ct < 2; ct++) {
        sc[ct] = __builtin_amdgcn_mfma_f32_16x16x32_bf16(qf[i][0], kfr[ct][0], sc[ct], 0, 0, 0);
        sc[ct] = __builtin_amdgcn_mfma_f32_16x16x32_bf16(qf[i][1], kfr[ct][1], sc[ct], 0, 0, 0);
      }
      float* Pw = Plds[w];
#pragma unroll
      for (int ct = 0; ct < 2; ct++) {
        int k = ks * 32 + ct * 16 + lm;
        int kh = (k * 293) >> 12;       // k/14, exact for k < ~580
        int kw2 = k - kh * 14;
        bool kval = (k < 196);
#pragma unroll
        for (int reg = 0; reg < 4; reg++) {
          int q = rt * 16 + quad * 4 + reg;
          int qh = (q * 293) >> 12;
          int qw = q - qh * 14;
          int th = qh - kh + 13; th = th < 0 ? 0 : th;   // pad cols can go to -2; masked anyway
          int tw = qw - kw2 + 13;
          float bh = bf2f(rhlds[q * 28 + th]);
          float bw = bf2f(rwlds[q * 28 + tw]);
          float s = sc[ct][reg] * SCALEF + bh + bw;
          float p = kval ? __expf(s) : 0.0f;
          lsum[i][reg] += p;
          int prow = quad * 4 + reg;
          int col = ct * 16 + lm;
          Pw[prow * 32 + (((col >> 2) ^ (prow & 7)) * 4) + (col & 3)] = p;
        }
      }
      // P A-frag: row=lm, k=quad*8+j (in-wave DS ordering: writes above land first)
      floatx4 pa = *(const floatx4*)&Pw[lm * 32 + (((2 * quad) ^ (lm & 7)) * 4)];
      floatx4 pb = *(const floatx4*)&Pw[lm * 32 + (((2 * quad + 1) ^ (lm & 7)) * 4)];
      short8 pfr;
#pragma unroll
      for (int j = 0; j < 4; j++) {
        pfr[j]     = (short)f2bf(pa[j]);
        pfr[4 + j] = (short)f2bf(pb[j]);
      }
#pragma unroll
      for (int dt = 0; dt < 4; dt++)
        oacc[i][dt] = __builtin_amdgcn_mfma_f32_16x16x32_bf16(pfr, vfr[dt], oacc[i][dt], 0, 0, 0);
    }
  }

  // ---- epilogue: row-sum across the 16 lanes of each quad group, normalize, store
#pragma unroll
  for (int i = 0; i < 4; i++) {
    int rt = w + 4 * i;
    if (rt > 12) continue;
#pragma unroll
    for (int reg = 0; reg < 4; reg++) {
      float v = lsum[i][reg];
      v += __shfl_xor(v, 1);
      v += __shfl_xor(v, 2);
      v += __shfl_xor(v, 4);
      v += __shfl_xor(v, 8);
      float inv = 1.0f / v;
      int row = rt * 16 + quad * 4 + reg;
      if (row < 196) {
        u16* op = out + (base + row) * C + h * HD + lm;
#pragma unroll
        for (int dt = 0; dt < 4; dt++) op[dt * 16] = f2bf(oacc[i][dt][reg] * inv);
      }
    }
  }
}

// ---------------------------------------------------------------- launch
extern "C" void kernel_launch(void* const* d_in, const int* in_sizes, int n_in,
                              void* d_out, int out_size, void* d_ws, size_t ws_size,
                              hipStream_t stream)
{
  const float* x      = (const float*)d_in[0];
  const float* qkv_w  = (const float*)d_in[1];
  const float* qkv_b  = (const float*)d_in[2];
  const float* proj_w = (const float*)d_in[3];
  const float* proj_b = (const float*)d_in[4];
  const float* rel_h  = (const float*)d_in[5];
  const float* rel_w  = (const float*)d_in[6];
  const float* n1w    = (const float*)d_in[7];
  const float* n1b    = (const float*)d_in[8];
  const float* n2w    = (const float*)d_in[9];
  const float* n2b    = (const float*)d_in[10];
  const float* fc1_w  = (const float*)d_in[11];
  const float* fc1_b  = (const float*)d_in[12];
  const float* fc2_w  = (const float*)d_in[13];
  const float* fc2_b  = (const float*)d_in[14];

  // workspace: [W0: M*384 bf16][W1: M*1536 bf16][W2: M*384 f32][WT: weights bf16]
  u16*  W0 = (u16*)d_ws;
  u16*  W1 = (u16*)((char*)d_ws + 86704128);
  float* W2 = (float*)((char*)d_ws + 86704128 + 346816512);
  u16*  WT = (u16*)((char*)d_ws + 86704128 + 346816512 + 173408256);
  u16* qkv_wT  = WT;                   // [1152,384]
  u16* proj_wT = qkv_wT + 442368;      // [384,384]
  u16* fc1_wT  = proj_wT + 147456;     // [1536,384]
  u16* fc2_wT  = fc1_wT + 589824;      // [384,1536]

  conv_t_kernel<<<dim3(NQKV / 32, C / 32), 256, 0, stream>>>(qkv_w, qkv_wT, C, NQKV);
  conv_t_kernel<<<dim3(C / 32, C / 32), 256, 0, stream>>>(proj_w, proj_wT, C, C);
  conv_t_kernel<<<dim3(NFC / 32, C / 32), 256, 0, stream>>>(fc1_w, fc1_wT, C, NFC);
  conv_t_kernel<<<dim3(C / 32, NFC / 32), 256, 0, stream>>>(fc2_w, fc2_wT, NFC, C);

  // 1. LN1 + window partition -> bf16
  ln_kernel<true><<<TOKENS, 128, 0, stream>>>(x, n1w, n1b, W0);
  // 2. qkv = xw @ qkv_w + b  -> bf16 [M,1152]
  gemm_bf16<0><<<dim3(NQKV / 128, TOKENS / 128), 256, 0, stream>>>(
      W0, qkv_wT, qkv_b, nullptr, W1, NQKV, C);
  // 3. MFMA attention -> attn_out bf16 (windowed rows) in W0
  attn_kernel<<<576 * HEADS, 256, 0, stream>>>(W1, rel_h, rel_w, W0);
  // 4. x2 = x + attn_out @ proj_w + b (unpartition remap) -> f32
  gemm_bf16<1><<<dim3(C / 128, TOKENS / 128), 256, 0, stream>>>(
      W0, proj_wT, proj_b, x, W2, C, C);
  // 5. LN2 -> bf16
  ln_kernel<false><<<TOKENS, 128, 0, stream>>>(W2, n2w, n2b, W0);
  // 6. h1 = gelu(xn2 @ fc1_w + b) -> bf16 [M,1536]
  gemm_bf16<2><<<dim3(NFC / 128, TOKENS / 128), 256, 0, stream>>>(
      W0, fc1_wT, fc1_b, nullptr, W1, NFC, C);
  // 7. out = x2 + h1 @ fc2_w + b -> f32
  gemm_bf16<3><<<dim3(C / 128, TOKENS / 128), 256, 0, stream>>>(
      W1, fc2_wT, fc2_b, W2, (float*)d_out, C, NFC);
}

// Round 3
// 1386.017 us; speedup vs baseline: 3.4734x; 1.0691x over previous
//
#include <hip/hip_runtime.h>
#include <math.h>

#define TOKENS 112896
#define C      384
#define NQKV   1152
#define NFC    1536
#define HEADS  6
#define HD     64
#define WIN    14
#define L      196
#define NWS    24
#define SCALEF 0.125f

typedef unsigned int  u32;
typedef unsigned short u16;
typedef short short8 __attribute__((ext_vector_type(8)));
typedef float floatx4 __attribute__((ext_vector_type(4)));

__device__ __forceinline__ u16 f2bf(float f) {
  u32 u = __float_as_uint(f);
  u += 0x7FFFu + ((u >> 16) & 1u);   // RNE (finite values only here)
  return (u16)(u >> 16);
}

__device__ __forceinline__ float bf2f(u16 v) {
  return __uint_as_float((u32)v << 16);
}

// exact-GELU via A&S 7.1.26 erf approx (|err| < 1.5e-7, branch-free):
// ~14 VALU ops vs ocml erff's ~35 with branches.
__device__ __forceinline__ float gelu_f(float v) {
  float z = fabsf(v) * 0.70710678118654752f;
  float t = 1.0f / (1.0f + 0.3275911f * z);
  float poly = t * (0.254829592f + t * (-0.284496736f + t * (1.421413741f +
               t * (-1.453152027f + t * 1.061405429f))));
  float erfv = 1.0f - poly * __expf(-z * z);   // erf(|z|)
  erfv = copysignf(erfv, v);
  return 0.5f * v * (1.0f + erfv);
}

// async 16B global->LDS copy; lds base must be wave-uniform, HW adds lane*16
__device__ __forceinline__ void async16(u16* lds, const u16* g) {
  __builtin_amdgcn_global_load_lds((const __attribute__((address_space(1))) void*)g,
                                   (__attribute__((address_space(3))) void*)lds,
                                   16, 0, 0);
}

__device__ __forceinline__ int win_to_tok(int r) {
  int n = r / L, l = r % L;
  int wh = n / NWS, ww = n % NWS;
  int ih = l / WIN, iw = l % WIN;
  return (wh * WIN + ih) * 336 + ww * WIN + iw;
}

// ---------------------------------------------------------------- weight T+cvt
// out[n*K+k] = bf16(in[k*N+n]); 32x32 LDS tile transpose, coalesced both sides.
__global__ __launch_bounds__(256) void conv_t_kernel(const float* __restrict__ in,
    u16* __restrict__ out, int K, int N)
{
  __shared__ u16 tile[32][33];
  const int kb = blockIdx.y * 32, nb = blockIdx.x * 32;
  const int tx = threadIdx.x & 31, ty = threadIdx.x >> 5;
#pragma unroll
  for (int i = 0; i < 4; i++) {
    int k = kb + ty + i * 8;
    tile[ty + i * 8][tx] = f2bf(in[(size_t)k * N + nb + tx]);
  }
  __syncthreads();
#pragma unroll
  for (int i = 0; i < 4; i++) {
    int n = nb + ty + i * 8;
    out[(size_t)n * K + kb + tx] = tile[tx][ty + i * 8];
  }
}

// ---------------------------------------------------------------- LayerNorm
template<bool PERMUTE>
__global__ __launch_bounds__(128) void ln_kernel(const float* __restrict__ x,
    const float* __restrict__ w, const float* __restrict__ b,
    u16* __restrict__ out)
{
  const int t = blockIdx.x;
  const int tid = threadIdx.x;
  const float* xr = x + (size_t)t * C;
  float v0 = xr[tid], v1 = xr[tid + 128], v2 = xr[tid + 256];
  float s  = v0 + v1 + v2;
  float ss = v0 * v0 + v1 * v1 + v2 * v2;
#pragma unroll
  for (int off = 32; off > 0; off >>= 1) {
    s  += __shfl_down(s, off);
    ss += __shfl_down(ss, off);
  }
  __shared__ float red[4];
  if ((tid & 63) == 0) { red[(tid >> 6) * 2 + 0] = s; red[(tid >> 6) * 2 + 1] = ss; }
  __syncthreads();
  float S  = red[0] + red[2];
  float SS = red[1] + red[3];
  float mean = S * (1.0f / C);
  float var  = SS * (1.0f / C) - mean * mean;
  float rstd = rsqrtf(var + 1e-5f);
  size_t orow;
  if (PERMUTE) {
    int h_ = t / 336, w_ = t % 336;
    int wh = h_ / WIN, ih = h_ % WIN;
    int ww = w_ / WIN, iw = w_ % WIN;
    orow = (size_t)((wh * NWS + ww) * L + ih * WIN + iw);
  } else {
    orow = (size_t)t;
  }
  u16* op = out + orow * C;
  op[tid]       = f2bf((v0 - mean) * rstd * w[tid]       + b[tid]);
  op[tid + 128] = f2bf((v1 - mean) * rstd * w[tid + 128] + b[tid + 128]);
  op[tid + 256] = f2bf((v2 - mean) * rstd * w[tid + 256] + b[tid + 256]);
}

// ---------------------------------------------------------------- bf16 MFMA GEMM
// A[M,K] bf16 row-major, Bt[N,K] bf16 row-major. 128x128 tile, BK=32,
// double-buffered LDS (32 KB total -> 4-5 blocks/CU, 16-20 waves: per-step
// load latency at the barrier hidden by cross-block TLP). Rows = 64B with 4
// granules of 16B; source pre-swizzled granule g^((r>>1)&3) so the 64-lane
// ds_read_b128 spreads evenly over all 8 bank-slots (conflict-free) while
// LDS stays linear for global_load_lds. Bijective XCD swizzle for A-panel L2.
template<int MODE>
__global__ __launch_bounds__(256, 4) void gemm_bf16(
    const u16* __restrict__ A, const u16* __restrict__ Bt,
    const float* __restrict__ bias, const float* __restrict__ res,
    void* __restrict__ outv, int N, int K)
{
  __shared__ u16 As[2][128 * 32];
  __shared__ u16 Bs[2][128 * 32];
  const int tid = threadIdx.x;
  const int w = tid >> 6, l = tid & 63;

  // bijective XCD-chunked remap of linear block id
  const int nwg = gridDim.x * gridDim.y;
  int lin = blockIdx.y * gridDim.x + blockIdx.x;
  {
    int q8 = nwg >> 3, r8 = nwg & 7;
    int xcd = lin & 7, sub = lin >> 3;
    lin = (xcd < r8 ? xcd * (q8 + 1) : r8 * (q8 + 1) + (xcd - r8) * q8) + sub;
  }
  const int bx = lin % gridDim.x, by = lin / gridDim.x;
  const int bm = by * 128, bn = bx * 128;

  const int wm = (w >> 1) * 64, wn = (w & 1) * 64;
  const int lm = l & 15, quad = l >> 4;

  floatx4 acc[4][4] = {};

  // staging: issue q in {0,1}: t = q*256+tid; row r=t>>2, lds granule gl=t&3,
  // global source granule gl ^ ((r>>1)&3) (pre-swizzled source, linear LDS)
  const u16* Asrc[2]; const u16* Bsrc[2];
#pragma unroll
  for (int q = 0; q < 2; q++) {
    int t = q * 256 + tid;
    int r = t >> 2, gl = t & 3;
    int sg = gl ^ ((r >> 1) & 3);
    Asrc[q] = A  + (size_t)(bm + r) * K + sg * 8;
    Bsrc[q] = Bt + (size_t)(bn + r) * K + sg * 8;
  }
  u16* Ad[2]; u16* Bd[2];   // wave-uniform LDS bases (HW adds lane*16)
#pragma unroll
  for (int q = 0; q < 2; q++) {
    Ad[q] = &As[0][(q * 256 + w * 64) * 8];
    Bd[q] = &Bs[0][(q * 256 + w * 64) * 8];
  }
  const int bufoff = 128 * 32;   // u16 elements per buffer

  auto stage = [&](int buf, int kt) {
#pragma unroll
    for (int q = 0; q < 2; q++) {
      async16(Ad[q] + buf * bufoff, Asrc[q] + kt);
      async16(Bd[q] + buf * bufoff, Bsrc[q] + kt);
    }
  };

  // per-lane LDS read addresses (loop-invariant): row = tile*16+lm,
  // granule = quad ^ ((lm>>1)&3)   [== quad ^ ((r>>1)&3) since wm,i*16 vanish]
  const int xg = (quad ^ ((lm >> 1) & 3)) * 8;
  const u16* ard[4]; const u16* brd[4];
#pragma unroll
  for (int i = 0; i < 4; i++) {
    ard[i] = &As[0][(wm + i * 16 + lm) * 32 + xg];
    brd[i] = &Bs[0][(wn + i * 16 + lm) * 32 + xg];
  }

  const int nk = K >> 5;
  stage(0, 0);
  __syncthreads();   // vmcnt(0) drained by compiler: tile 0 resident

  for (int t = 0; t < nk; t++) {
    const int buf = t & 1;
    if (t + 1 < nk) stage(buf ^ 1, (t + 1) << 5);
    const int bo = buf * bufoff;
    short8 bfr[4];
#pragma unroll
    for (int j = 0; j < 4; j++) bfr[j] = *(const short8*)(brd[j] + bo);
#pragma unroll
    for (int i = 0; i < 4; i++) {
      short8 afr = *(const short8*)(ard[i] + bo);
#pragma unroll
      for (int j = 0; j < 4; j++)
        acc[i][j] = __builtin_amdgcn_mfma_f32_16x16x32_bf16(afr, bfr[j], acc[i][j], 0, 0, 0);
    }
    __syncthreads();   // prefetch landed + all reads of buf done
  }

  // epilogue; C/D layout: col = lane&15, row = quad*4 + reg
  const int colbase = bn + wn + lm;
  float bb[4];
#pragma unroll
  for (int j = 0; j < 4; j++) bb[j] = bias[colbase + j * 16];

#pragma unroll
  for (int i = 0; i < 4; i++) {
#pragma unroll
    for (int reg = 0; reg < 4; reg++) {
      int row = bm + wm + i * 16 + quad * 4 + reg;
      size_t ro;
      if (MODE == 1) ro = (size_t)win_to_tok(row) * N;
      else           ro = (size_t)row * N;
#pragma unroll
      for (int j = 0; j < 4; j++) {
        float v = acc[i][j][reg] + bb[j];
        int col = colbase + j * 16;
        if (MODE == 0) {
          ((u16*)outv)[ro + col] = f2bf(v);
        } else if (MODE == 1) {
          ((float*)outv)[ro + col] = v + res[ro + col];
        } else if (MODE == 2) {
          ((u16*)outv)[ro + col] = f2bf(gelu_f(v));
        } else {
          ((float*)outv)[ro + col] = v + res[ro + col];
        }
      }
    }
  }
}

// ---------------------------------------------------------------- MFMA Attention
// One block per (window, head); 4 waves, 256 threads; mfma_f32_16x16x32_bf16.
// (unchanged — not the current bottleneck)
__global__ __launch_bounds__(256, 2) void attn_kernel(
    const u16* __restrict__ qkv,
    const float* __restrict__ relh, const float* __restrict__ relw,
    u16* __restrict__ out)
{
  __shared__ float Plds[4][512];      // per-wave P tile [16][32] f32, 4-float-granule XOR swz
  __shared__ u16 rhlds[208 * 28];     // RH'[q][t] bf16
  __shared__ u16 rwlds[208 * 28];     // RW'[q][t] bf16
  __shared__ u16 Klds[32 * 64];       // K tile [kv][c] bf16, granule^(kv&7) swz
  __shared__ u16 Vtl[64 * 40];        // V^T tile [d][kv] bf16 (stride 40 for banks)

  const int n = blockIdx.x / HEADS;
  const int h = blockIdx.x % HEADS;
  const int tid = threadIdx.x;
  const int w = tid >> 6;
  const int l = tid & 63;
  const int lm = l & 15;
  const int quad = l >> 4;
  const size_t base = (size_t)n * L;

  // ---- Q A-fragments: registers for whole kernel (rows clamped; row>=196 discarded)
  short8 qf[4][2];
#pragma unroll
  for (int i = 0; i < 4; i++) {
    int rt = w + 4 * i;
    if (rt <= 12) {
      int row = rt * 16 + lm; if (row > 195) row = 195;
      const u16* qp = qkv + (base + row) * NQKV + h * HD + quad * 8;
#pragma unroll
      for (int kf = 0; kf < 2; kf++)
        qf[i][kf] = *(const short8*)(qp + kf * 32);
    }
  }

  // ---- RH'/RW' = Q @ rel_table^T -> LDS bf16 (per-wave rows; no barrier needed)
  {
    short8 tf[2][2][2];  // [tab][ct][kf]
#pragma unroll
    for (int tab = 0; tab < 2; tab++) {
      const float* tp = tab ? relw : relh;
#pragma unroll
      for (int ct = 0; ct < 2; ct++) {
        int t = ct * 16 + lm;
#pragma unroll
        for (int kf = 0; kf < 2; kf++) {
          short8 v = {0, 0, 0, 0, 0, 0, 0, 0};
          if (t < 27) {
            const float* p = tp + t * HD + kf * 32 + quad * 8;
            float4 a = *(const float4*)p;
            float4 b = *(const float4*)(p + 4);
            v[0] = (short)f2bf(a.x); v[1] = (short)f2bf(a.y);
            v[2] = (short)f2bf(a.z); v[3] = (short)f2bf(a.w);
            v[4] = (short)f2bf(b.x); v[5] = (short)f2bf(b.y);
            v[6] = (short)f2bf(b.z); v[7] = (short)f2bf(b.w);
          }
          tf[tab][ct][kf] = v;
        }
      }
    }
#pragma unroll
    for (int i = 0; i < 4; i++) {
      int rt = w + 4 * i;
      if (rt > 12) continue;
#pragma unroll
      for (int tab = 0; tab < 2; tab++) {
        u16* dst = tab ? rwlds : rhlds;
#pragma unroll
        for (int ct = 0; ct < 2; ct++) {
          floatx4 acc = {};
          acc = __builtin_amdgcn_mfma_f32_16x16x32_bf16(qf[i][0], tf[tab][ct][0], acc, 0, 0, 0);
          acc = __builtin_amdgcn_mfma_f32_16x16x32_bf16(qf[i][1], tf[tab][ct][1], acc, 0, 0, 0);
          int t = ct * 16 + lm;
          if (t < 28) {
#pragma unroll
            for (int reg = 0; reg < 4; reg++) {
              int q = rt * 16 + quad * 4 + reg;
              dst[q * 28 + t] = f2bf(acc[reg]);
            }
          }
        }
      }
    }
  }

  floatx4 oacc[4][4] = {};   // [i][dt]
  float lsum[4][4] = {};     // [i][reg]

#pragma unroll 1
  for (int ks = 0; ks < 7; ks++) {
    __syncthreads();   // all waves done reading Klds/Vtl from previous step
    // stage K [32][64], granule g -> g ^ (r&7)
    {
      int r = tid >> 3, g = tid & 7;
      int row = ks * 32 + r; if (row > 195) row = 195;
      uint4 kd = *(const uint4*)(qkv + (base + row) * NQKV + C + h * HD + g * 8);
      *(uint4*)&Klds[r * 64 + ((g ^ (r & 7)) * 8)] = kd;
    }
    // stage V^T [64][40]
    {
      int r = tid & 31, seg = tid >> 5;
      int row = ks * 32 + r; if (row > 195) row = 195;
      uint4 vd = *(const uint4*)(qkv + (base + row) * NQKV + 2 * C + h * HD + seg * 8);
      union { uint4 u; u16 s[8]; } vv; vv.u = vd;
#pragma unroll
      for (int j = 0; j < 8; j++) Vtl[(seg * 8 + j) * 40 + r] = vv.s[j];
    }
    __syncthreads();

    // K B-frags: B[c][kv], lane col=kv=ct*16+lm, c=kf*32+quad*8+j
    short8 kfr[2][2];
#pragma unroll
    for (int ct = 0; ct < 2; ct++) {
      int krow = ct * 16 + lm;
#pragma unroll
      for (int kf = 0; kf < 2; kf++)
        kfr[ct][kf] = *(const short8*)&Klds[krow * 64 + (((kf * 4 + quad) ^ (krow & 7)) * 8)];
    }
    // V B-frags: B[kv][d], lane col=d=dt*16+lm, kv=quad*8+j
    short8 vfr[4];
#pragma unroll
    for (int dt = 0; dt < 4; dt++)
      vfr[dt] = *(const short8*)&Vtl[(dt * 16 + lm) * 40 + quad * 8];

#pragma unroll
    for (int i = 0; i < 4; i++) {
      int rt = w + 4 * i;
      if (rt > 12) continue;
      // S tile: [16 q][32 kv]
      floatx4 sc[2] = {};
#pragma unroll
      for (int ct = 0; ct < 2; ct++) {
        sc[ct] = __builtin_amdgcn_mfma_f32_16x16x32_bf16(qf[i][0], kfr[ct][0], sc[ct], 0, 0, 0);
        sc[ct] = __builtin_amdgcn_mfma_f32_16x16x32_bf16(qf[i][1], kfr[ct][1], sc[ct], 0, 0, 0);
      }
      float* Pw = Plds[w];
#pragma unroll
      for (int ct = 0; ct < 2; ct++) {
        int k = ks * 32 + ct * 16 + lm;
        int kh = (k * 293) >> 12;       // k/14, exact for k < ~580
        int kw2 = k - kh * 14;
        bool kval = (k < 196);
#pragma unroll
        for (int reg = 0; reg < 4; reg++) {
          int q = rt * 16 + quad * 4 + reg;
          int qh = (q * 293) >> 12;
          int qw = q - qh * 14;
          int th = qh - kh + 13; th = th < 0 ? 0 : th;   // pad cols can go to -2; masked anyway
          int tw = qw - kw2 + 13;
          float bh = bf2f(rhlds[q * 28 + th]);
          float bw = bf2f(rwlds[q * 28 + tw]);
          float s = sc[ct][reg] * SCALEF + bh + bw;
          float p = kval ? __expf(s) : 0.0f;
          lsum[i][reg] += p;
          int prow = quad * 4 + reg;
          int col = ct * 16 + lm;
          Pw[prow * 32 + (((col >> 2) ^ (prow & 7)) * 4) + (col & 3)] = p;
        }
      }
      // P A-frag: row=lm, k=quad*8+j (in-wave DS ordering: writes above land first)
      floatx4 pa = *(const floatx4*)&Pw[lm * 32 + (((2 * quad) ^ (lm & 7)) * 4)];
      floatx4 pb = *(const floatx4*)&Pw[lm * 32 + (((2 * quad + 1) ^ (lm & 7)) * 4)];
      short8 pfr;
#pragma unroll
      for (int j = 0; j < 4; j++) {
        pfr[j]     = (short)f2bf(pa[j]);
        pfr[4 + j] = (short)f2bf(pb[j]);
      }
#pragma unroll
      for (int dt = 0; dt < 4; dt++)
        oacc[i][dt] = __builtin_amdgcn_mfma_f32_16x16x32_bf16(pfr, vfr[dt], oacc[i][dt], 0, 0, 0);
    }
  }

  // ---- epilogue: row-sum across the 16 lanes of each quad group, normalize, store
#pragma unroll
  for (int i = 0; i < 4; i++) {
    int rt = w + 4 * i;
    if (rt > 12) continue;
#pragma unroll
    for (int reg = 0; reg < 4; reg++) {
      float v = lsum[i][reg];
      v += __shfl_xor(v, 1);
      v += __shfl_xor(v, 2);
      v += __shfl_xor(v, 4);
      v += __shfl_xor(v, 8);
      float inv = 1.0f / v;
      int row = rt * 16 + quad * 4 + reg;
      if (row < 196) {
        u16* op = out + (base + row) * C + h * HD + lm;
#pragma unroll
        for (int dt = 0; dt < 4; dt++) op[dt * 16] = f2bf(oacc[i][dt][reg] * inv);
      }
    }
  }
}

// ---------------------------------------------------------------- launch
extern "C" void kernel_launch(void* const* d_in, const int* in_sizes, int n_in,
                              void* d_out, int out_size, void* d_ws, size_t ws_size,
                              hipStream_t stream)
{
  const float* x      = (const float*)d_in[0];
  const float* qkv_w  = (const float*)d_in[1];
  const float* qkv_b  = (const float*)d_in[2];
  const float* proj_w = (const float*)d_in[3];
  const float* proj_b = (const float*)d_in[4];
  const float* rel_h  = (const float*)d_in[5];
  const float* rel_w  = (const float*)d_in[6];
  const float* n1w    = (const float*)d_in[7];
  const float* n1b    = (const float*)d_in[8];
  const float* n2w    = (const float*)d_in[9];
  const float* n2b    = (const float*)d_in[10];
  const float* fc1_w  = (const float*)d_in[11];
  const float* fc1_b  = (const float*)d_in[12];
  const float* fc2_w  = (const float*)d_in[13];
  const float* fc2_b  = (const float*)d_in[14];

  // workspace: [W0: M*384 bf16][W1: M*1536 bf16][W2: M*384 f32][WT: weights bf16]
  u16*  W0 = (u16*)d_ws;
  u16*  W1 = (u16*)((char*)d_ws + 86704128);
  float* W2 = (float*)((char*)d_ws + 86704128 + 346816512);
  u16*  WT = (u16*)((char*)d_ws + 86704128 + 346816512 + 173408256);
  u16* qkv_wT  = WT;                   // [1152,384]
  u16* proj_wT = qkv_wT + 442368;      // [384,384]
  u16* fc1_wT  = proj_wT + 147456;     // [1536,384]
  u16* fc2_wT  = fc1_wT + 589824;      // [384,1536]

  conv_t_kernel<<<dim3(NQKV / 32, C / 32), 256, 0, stream>>>(qkv_w, qkv_wT, C, NQKV);
  conv_t_kernel<<<dim3(C / 32, C / 32), 256, 0, stream>>>(proj_w, proj_wT, C, C);
  conv_t_kernel<<<dim3(NFC / 32, C / 32), 256, 0, stream>>>(fc1_w, fc1_wT, C, NFC);
  conv_t_kernel<<<dim3(C / 32, NFC / 32), 256, 0, stream>>>(fc2_w, fc2_wT, NFC, C);

  // 1. LN1 + window partition -> bf16
  ln_kernel<true><<<TOKENS, 128, 0, stream>>>(x, n1w, n1b, W0);
  // 2. qkv = xw @ qkv_w + b  -> bf16 [M,1152]
  gemm_bf16<0><<<dim3(NQKV / 128, TOKENS / 128), 256, 0, stream>>>(
      W0, qkv_wT, qkv_b, nullptr, W1, NQKV, C);
  // 3. MFMA attention -> attn_out bf16 (windowed rows) in W0
  attn_kernel<<<576 * HEADS, 256, 0, stream>>>(W1, rel_h, rel_w, W0);
  // 4. x2 = x + attn_out @ proj_w + b (unpartition remap) -> f32
  gemm_bf16<1><<<dim3(C / 128, TOKENS / 128), 256, 0, stream>>>(
      W0, proj_wT, proj_b, x, W2, C, C);
  // 5. LN2 -> bf16
  ln_kernel<false><<<TOKENS, 128, 0, stream>>>(W2, n2w, n2b, W0);
  // 6. h1 = gelu(xn2 @ fc1_w + b) -> bf16 [M,1536]
  gemm_bf16<2><<<dim3(NFC / 128, TOKENS / 128), 256, 0, stream>>>(
      W0, fc1_wT, fc1_b, nullptr, W1, NFC, C);
  // 7. out = x2 + h1 @ fc2_w + b -> f32
  gemm_bf16<3><<<dim3(C / 128, TOKENS / 128), 256, 0, stream>>>(
      W1, fc2_wT, fc2_b, W2, (float*)d_out, C, NFC);
}